// Round 9
// baseline (85.068 us; speedup 1.0000x reference)
//
#include <hip/hip_runtime.h>

#define N_NODES 16384
#define NE 524288
#define KDIM 1152          // IN*NG + IN
#define KPAD 1160          // padded LDS row (ushorts)
#define KSTEPS 36          // 1152 / 32
#define NBUCK 512          // buckets of 32 nodes
#define SBLK 512           // hist/bin blocks; each owns 1024 edges = 2048 entries
#define BCAP2 2816         // words per bucket region (mean 2048, +17 sigma)
#define MROW 516           // padded LDS row stride (words) for degb bitmask
#define DCAP 256           // per-node dedup'd neighbor capacity (mean 64)

typedef unsigned int uint32;
typedef unsigned short ushort;
typedef __attribute__((ext_vector_type(8))) short bf16x8;
typedef __attribute__((ext_vector_type(4))) float f32x4;

__device__ __forceinline__ ushort f2bf(float f) {
    unsigned u = __float_as_uint(f);
    unsigned r = (u + 0x7fffu + ((u >> 16) & 1u)) >> 16;
    return (ushort)r;
}
__device__ __forceinline__ float bflo(uint32 u) {
    return __uint_as_float(u << 16);
}
__device__ __forceinline__ float bfhi(uint32 u) {
    return __uint_as_float(u & 0xffff0000u);
}

// ===== launch 1: per-(block,bucket) histogram (0..511) + weight pack (512..1087) =====
__global__ __launch_bounds__(256) void preA_kernel(
    const int* __restrict__ ei, uint32* __restrict__ cntT,
    const float* __restrict__ sw, const float* __restrict__ bw,
    ushort* __restrict__ Wp) {
    const int t = threadIdx.x;
    if (blockIdx.x >= SBLK) {
        int idx = (blockIdx.x - SBLK) * 256 + t;   // 0 .. 147455
        int i  = idx & 7;
        int l  = (idx >> 3) & 63;
        int ct = (idx >> 9) & 7;
        int kk = idx >> 12;
        int k   = kk * 32 + ((l >> 4) << 3) + i;
        int col = ct * 16 + (l & 15);
        float v = (k < 1024) ? sw[col * 1024 + k] : bw[col * 128 + (k - 1024)];
        Wp[idx] = f2bf(v);
        return;
    }
    __shared__ int hcnt[NBUCK];
    hcnt[t] = 0;
    hcnt[t + 256] = 0;
    __syncthreads();
#pragma unroll
    for (int k = 0; k < 4; ++k) {
        int e = blockIdx.x * 1024 + k * 256 + t;
        int a = ei[e];
        int b = ei[NE + e];
        atomicAdd(&hcnt[a >> 5], 1);
        atomicAdd(&hcnt[b >> 5], 1);
    }
    __syncthreads();
    // transposed table: cntT[q][b]; scattered async 4B writes
    cntT[(size_t)t * SBLK + blockIdx.x]         = (uint32)hcnt[t];
    cntT[(size_t)(t + 256) * SBLK + blockIdx.x] = (uint32)hcnt[t + 256];
}

// ===== launch 2: per-bucket column scan -> pos[b][q], bsize[q] =====
__global__ __launch_bounds__(256) void preB_kernel(
    const uint32* __restrict__ cntT, uint32* __restrict__ pos,
    uint32* __restrict__ bsize) {
    __shared__ int sc[SBLK];
    const int t = threadIdx.x;
    const int q = blockIdx.x;
    sc[t]       = (int)cntT[(size_t)q * SBLK + t];          // coalesced
    sc[t + 256] = (int)cntT[(size_t)q * SBLK + t + 256];
    __syncthreads();
    const int c0 = sc[t];
    const int c1 = sc[t + 256];
    for (int off = 1; off < SBLK; off <<= 1) {
        int v0 = sc[t], v1 = sc[t + 256];
        int a0 = (t >= off) ? sc[t - off] : 0;
        int a1 = sc[t + 256 - off];
        __syncthreads();
        sc[t] = v0 + a0;
        sc[t + 256] = v1 + a1;
        __syncthreads();
    }
    const uint32 base = (uint32)q * BCAP2;
    pos[(size_t)t * NBUCK + q]         = base + (uint32)(sc[t] - c0);
    pos[(size_t)(t + 256) * NBUCK + q] = base + (uint32)(sc[t + 256] - c1);
    if (t == 0) {
        int total = sc[511];
        bsize[q] = (uint32)(total > BCAP2 ? BCAP2 : total);
    }
}

// ===== launch 3: bucket-major bin (0..511) + FastKAN support (512..1535) =====
// shared LDS arena: max(bin 4 KB ; support 16*KPAD*2 = 37,120 B)
__global__ __launch_bounds__(256) void midC_kernel(
    const int* __restrict__ ei, const uint32* __restrict__ pos,
    uint32* __restrict__ ebuf, const float* __restrict__ x,
    const float* __restrict__ gamma, const float* __restrict__ beta,
    const ushort* __restrict__ Wp, const float* __restrict__ base_b,
    ushort* __restrict__ S) {
    __shared__ __align__(16) ushort smem[16 * KPAD];        // 37,120 B
    const int t = threadIdx.x;
    const int lane = t & 63;
    const int w = t >> 6;

    if (blockIdx.x < SBLK) {
        // ---- bin: scattered writes into bucket-contiguous regions ----
        int* hcnt = (int*)smem;                              // [512]
        uint32* lpos = (uint32*)smem + NBUCK;                // [512]
        const int b = blockIdx.x;
        lpos[t]       = pos[(size_t)b * NBUCK + t];          // coalesced
        lpos[t + 256] = pos[(size_t)b * NBUCK + t + 256];
        hcnt[t] = 0;
        hcnt[t + 256] = 0;
        __syncthreads();
#pragma unroll
        for (int k = 0; k < 4; ++k) {
            int e = b * 1024 + k * 256 + t;
            int a = ei[e];
            int bb = ei[NE + e];
            int qa = a >> 5;
            int sl = atomicAdd(&hcnt[qa], 1);
            uint32 idx = lpos[qa] + (uint32)sl;
            if (idx < (uint32)(qa + 1) * BCAP2)
                ebuf[idx] = ((uint32)(a & 31) << 14) | (uint32)bb;
            int qb = bb >> 5;
            sl = atomicAdd(&hcnt[qb], 1);
            idx = lpos[qb] + (uint32)sl;
            if (idx < (uint32)(qb + 1) * BCAP2)
                ebuf[idx] = ((uint32)(bb & 31) << 14) | (uint32)a;
        }
        return;
    }

    // ---- support: 16 nodes/block, FastKAN basis + bf16 MFMA (unscaled S) ----
    ushort* Bs = smem;                                       // [16][KPAD]
    const int nodeBase = (blockIdx.x - SBLK) * 16;

    const float g0 = gamma[lane], g1 = gamma[lane + 64];
    const float be0 = beta[lane], be1 = beta[lane + 64];

    for (int n = w * 4; n < w * 4 + 4; ++n) {
        const int row = nodeBase + n;
        float f0 = x[(size_t)row * 128 + lane];
        float f1 = x[(size_t)row * 128 + lane + 64];
        float s = f0 + f1;
#pragma unroll
        for (int o = 32; o; o >>= 1) s += __shfl_xor(s, o);
        float mu = s * 0.0078125f;
        float d0 = f0 - mu, d1 = f1 - mu;
        float v = d0 * d0 + d1 * d1;
#pragma unroll
        for (int o = 32; o; o >>= 1) v += __shfl_xor(v, o);
        float rstd = rsqrtf(v * 0.0078125f + 1e-5f);
        float h0 = d0 * rstd * g0 + be0;
        float h1 = d1 * rstd * g1 + be1;
        ushort pk0[8] __attribute__((aligned(16)));
        ushort pk1[8] __attribute__((aligned(16)));
#pragma unroll
        for (int g = 0; g < 8; ++g) {
            float gv = -2.0f + (float)g * (4.0f / 7.0f);
            float z0 = (h0 - gv) * 1.75f;
            float z1 = (h1 - gv) * 1.75f;
            pk0[g] = f2bf(__expf(-z0 * z0));
            pk1[g] = f2bf(__expf(-z1 * z1));
        }
        *reinterpret_cast<uint4*>(&Bs[n * KPAD + lane * 8]) =
            *reinterpret_cast<const uint4*>(pk0);
        *reinterpret_cast<uint4*>(&Bs[n * KPAD + (lane + 64) * 8]) =
            *reinterpret_cast<const uint4*>(pk1);
        Bs[n * KPAD + 1024 + lane]      = f2bf(f0 / (1.0f + __expf(-f0)));
        Bs[n * KPAD + 1024 + lane + 64] = f2bf(f1 / (1.0f + __expf(-f1)));
    }
    __syncthreads();

    const int ct0 = w * 2;
    f32x4 acc0 = {0.f, 0.f, 0.f, 0.f};
    f32x4 acc1 = {0.f, 0.f, 0.f, 0.f};
    const ushort* ArowBase = &Bs[(lane & 15) * KPAD + (lane >> 4) * 8];
    const bf16x8* Wv = (const bf16x8*)Wp;
#pragma unroll 4
    for (int kk = 0; kk < KSTEPS; ++kk) {
        bf16x8 a = *reinterpret_cast<const bf16x8*>(ArowBase + kk * 32);
        bf16x8 b0 = Wv[(size_t)(kk * 8 + ct0) * 64 + lane];
        bf16x8 b1 = Wv[(size_t)(kk * 8 + ct0 + 1) * 64 + lane];
        acc0 = __builtin_amdgcn_mfma_f32_16x16x32_bf16(a, b0, acc0, 0, 0, 0);
        acc1 = __builtin_amdgcn_mfma_f32_16x16x32_bf16(a, b1, acc1, 0, 0, 0);
    }

    const int col0 = ct0 * 16 + (lane & 15);
    const int rbase = (lane >> 4) * 4;
    const float bb0 = base_b[col0];
    const float bb1 = base_b[col0 + 16];
#pragma unroll
    for (int r = 0; r < 4; ++r) {
        const int row = nodeBase + rbase + r;
        S[(size_t)row * 128 + col0]      = f2bf(acc0[r] + bb0);
        S[(size_t)row * 128 + col0 + 16] = f2bf(acc1[r] + bb1);
    }
}

// ===== launch 4: per-bucket LDS bitmask from CONTIGUOUS bucket run -> dedup'd CSR =====
__global__ __launch_bounds__(256) void degb_kernel(
    const uint32* __restrict__ ebuf, const uint32* __restrict__ bsize,
    float* __restrict__ dis, int* __restrict__ degarr,
    ushort* __restrict__ dadj) {
    __shared__ uint32 mask[32 * MROW];              // 66,048 B
    const int t = threadIdx.x;
    const int bkt = blockIdx.x;
    for (int i = t; i < 32 * MROW; i += 256) mask[i] = 0;
    __syncthreads();

    const int n = (int)bsize[bkt];
    const uint32* p = ebuf + (size_t)bkt * BCAP2;
    for (int idx = t; idx < n; idx += 256) {
        uint32 e = p[idx];
        atomicOr(&mask[(e >> 14) * MROW + ((e & 16383) >> 5)], 1u << (e & 31));
    }
    __syncthreads();

    const int lane = t & 63;
    const int w = t >> 6;
    for (int nn = w * 8; nn < w * 8 + 8; ++nn) {
        const uint32* row = &mask[nn * MROW];
        uint32 wd[8];
        int c = 0;
#pragma unroll
        for (int j = 0; j < 8; ++j) {
            wd[j] = row[lane + 64 * j];
            c += __popc(wd[j]);
        }
        int inc = c;
#pragma unroll
        for (int o = 1; o < 64; o <<= 1) {
            int v = __shfl_up(inc, o);
            if (lane >= o) inc += v;
        }
        int total = __shfl(inc, 63);
        int ppos = inc - c;
        const int node = bkt * 32 + nn;
        if (lane == 0) {
            dis[node] = rsqrtf((float)total);
            degarr[node] = total > DCAP ? DCAP : total;
        }
        ushort* drow = dadj + (size_t)node * DCAP;
#pragma unroll
        for (int j = 0; j < 8; ++j) {
            uint32 bits = wd[j];
            int base = (lane + 64 * j) * 32;
            while (bits) {
                int b = __ffs(bits) - 1;
                bits &= bits - 1;
                if (ppos < DCAP) drow[ppos] = (ushort)(base + b);
                ++ppos;
            }
        }
    }
}

// ===== launch 5: aggregation, out[i] = dis_i * sum_j dis_j*S_j + bias =====
__global__ __launch_bounds__(256) void aggregate_kernel(
    const int* __restrict__ degarr, const ushort* __restrict__ dadj,
    const ushort* __restrict__ S, const float* __restrict__ dis,
    const float* __restrict__ bias, float* __restrict__ out) {
    __shared__ ushort lst[2][DCAP];
    __shared__ float part[2][2][128];
    const int t = threadIdx.x;
    const int g = t >> 7;
    const int tl = t & 127;
    const int i = blockIdx.x * 2 + g;

    const int total = degarr[i];
    const ushort* drow = dadj + (size_t)i * DCAP;
    if (tl < total) lst[g][tl] = drow[tl];
    if (tl + 128 < total) lst[g][tl + 128] = drow[tl + 128];
    __syncthreads();

    const int lane = t & 63;
    const int wv = (t >> 6) & 1;
    const uint32* S32 = (const uint32*)S;            // row stride 64 uints
    float a0 = 0.f, a1 = 0.f;
    int idx = wv;
    for (; idx + 6 < total; idx += 8) {
        int j0 = lst[g][idx], j1 = lst[g][idx + 2];
        int j2 = lst[g][idx + 4], j3 = lst[g][idx + 6];
        float d0 = dis[j0], d1 = dis[j1], d2 = dis[j2], d3 = dis[j3];
        uint32 u0 = S32[(size_t)j0 * 64 + lane];
        uint32 u1 = S32[(size_t)j1 * 64 + lane];
        uint32 u2 = S32[(size_t)j2 * 64 + lane];
        uint32 u3 = S32[(size_t)j3 * 64 + lane];
        a0 += (d0 * bflo(u0) + d1 * bflo(u1)) + (d2 * bflo(u2) + d3 * bflo(u3));
        a1 += (d0 * bfhi(u0) + d1 * bfhi(u1)) + (d2 * bfhi(u2) + d3 * bfhi(u3));
    }
    for (; idx < total; idx += 2) {
        int j = lst[g][idx];
        float d = dis[j];
        uint32 u = S32[(size_t)j * 64 + lane];
        a0 += d * bflo(u);
        a1 += d * bfhi(u);
    }
    part[g][wv][lane * 2]     = a0;
    part[g][wv][lane * 2 + 1] = a1;
    __syncthreads();

    float v = part[g][0][tl] + part[g][1][tl];
    out[(size_t)i * 128 + tl] = v * dis[i] + bias[tl];
}

extern "C" void kernel_launch(void* const* d_in, const int* in_sizes, int n_in,
                              void* d_out, int out_size, void* d_ws, size_t ws_size,
                              hipStream_t stream) {
    const float* x        = (const float*)d_in[0];
    const int*   ei       = (const int*)d_in[1];
    const float* ln_gamma = (const float*)d_in[2];
    const float* ln_beta  = (const float*)d_in[3];
    const float* spline_w = (const float*)d_in[4];
    const float* base_w   = (const float*)d_in[5];
    const float* base_b   = (const float*)d_in[6];
    const float* bias     = (const float*)d_in[7];
    float* out = (float*)d_out;

    char* ws = (char*)d_ws;
    const size_t WP_OFF   = 0;             //    294,912 B
    const size_t DIS_OFF  = 294912;        //     65,536 B
    const size_t DEG_OFF  = 360448;        //     65,536 B
    const size_t DADJ_OFF = 425984;        //  8,388,608 B
    const size_t CNTT_OFF = 8814592;       //  1,048,576 B
    const size_t POS_OFF  = 9863168;       //  1,048,576 B
    const size_t BSZ_OFF  = 10911744;      //      4,096 B
    const size_t EBUF_OFF = 10915840;      //  5,767,168 B
    const size_t S_OFF    = 16683008;      //  4,194,304 B
    const size_t NEEDED   = 20877312;
    if (ws_size < NEEDED) return;

    ushort* Wp     = (ushort*)(ws + WP_OFF);
    float*  dis    = (float*)(ws + DIS_OFF);
    int*    degarr = (int*)(ws + DEG_OFF);
    ushort* dadj   = (ushort*)(ws + DADJ_OFF);
    uint32* cntT   = (uint32*)(ws + CNTT_OFF);
    uint32* pos    = (uint32*)(ws + POS_OFF);
    uint32* bsize  = (uint32*)(ws + BSZ_OFF);
    uint32* ebuf   = (uint32*)(ws + EBUF_OFF);
    ushort* S      = (ushort*)(ws + S_OFF);

    preA_kernel<<<SBLK + 576, 256, 0, stream>>>(ei, cntT, spline_w, base_w, Wp);
    preB_kernel<<<NBUCK, 256, 0, stream>>>(cntT, pos, bsize);
    midC_kernel<<<SBLK + N_NODES / 16, 256, 0, stream>>>(
        ei, pos, ebuf, x, ln_gamma, ln_beta, Wp, base_b, S);
    degb_kernel<<<NBUCK, 256, 0, stream>>>(ebuf, bsize, dis, degarr, dadj);
    aggregate_kernel<<<N_NODES / 2, 256, 0, stream>>>(degarr, dadj, S, dis,
                                                      bias, out);
}

// Round 10
// 68.800 us; speedup vs baseline: 1.2365x; 1.2365x over previous
//
#include <hip/hip_runtime.h>

#define N_NODES 16384
#define NE 524288
#define KDIM 1152          // IN*NG + IN
#define KPAD 1160          // padded LDS row (ushorts): stride 2320 B breaks banks
#define KSTEPS 36          // 1152 / 32
#define NBUCK 1024         // buckets of 16 nodes
#define SBLK 512           // sort blocks; each owns 1024 edges = 2048 entries
#define SPB 2048           // directed entries per sort block (exact)
#define MROW 516           // padded LDS row stride (words) for degb bitmask
#define DCAP 256           // per-node dedup'd neighbor capacity (mean 64)

typedef unsigned int uint32;
typedef unsigned short ushort;
typedef __attribute__((ext_vector_type(8))) short bf16x8;
typedef __attribute__((ext_vector_type(4))) float f32x4;

__device__ __forceinline__ ushort f2bf(float f) {
    unsigned u = __float_as_uint(f);
    unsigned r = (u + 0x7fffu + ((u >> 16) & 1u)) >> 16;
    return (ushort)r;
}
__device__ __forceinline__ float bflo(uint32 u) {
    return __uint_as_float(u << 16);
}
__device__ __forceinline__ float bfhi(uint32 u) {
    return __uint_as_float(u & 0xffff0000u);
}

// ===== launch 1: in-LDS bucket sort (blocks 0..511) + weight pack (512..1087) =====
__global__ __launch_bounds__(256) void pre_kernel(
    const int* __restrict__ ei, uint32* __restrict__ ebuf,
    uint32* __restrict__ ocnt, const float* __restrict__ sw,
    const float* __restrict__ bw, ushort* __restrict__ Wp) {
    const int t = threadIdx.x;
    if (blockIdx.x >= SBLK) {
        // ---- transw: Wp[((kk*8+ct)*64+lane)*8+i] = bf16(W[k][col]) ----
        int idx = (blockIdx.x - SBLK) * 256 + t;   // 0 .. 147455
        int i  = idx & 7;
        int l  = (idx >> 3) & 63;
        int ct = (idx >> 9) & 7;
        int kk = idx >> 12;
        int k   = kk * 32 + ((l >> 4) << 3) + i;
        int col = ct * 16 + (l & 15);
        float v = (k < 1024) ? sw[col * 1024 + k] : bw[col * 128 + (k - 1024)];
        Wp[idx] = f2bf(v);
        return;
    }
    __shared__ int hcnt[NBUCK];                    // 4 KB
    __shared__ int lbase[NBUCK];                   // 4 KB
    __shared__ int ps[256];                        // 1 KB
    __shared__ uint32 st[SPB];                     // 8 KB
    for (int q = t; q < NBUCK; q += 256) hcnt[q] = 0;
    __syncthreads();

    int bk[8], sl[8];
    uint32 pk[8];
#pragma unroll
    for (int k = 0; k < 4; ++k) {
        int e = blockIdx.x * 1024 + k * 256 + t;
        int a = ei[e];
        int b = ei[NE + e];
        bk[2 * k]     = a >> 4;
        pk[2 * k]     = ((uint32)(a & 15) << 14) | (uint32)b;
        bk[2 * k + 1] = b >> 4;
        pk[2 * k + 1] = ((uint32)(b & 15) << 14) | (uint32)a;
        sl[2 * k]     = atomicAdd(&hcnt[bk[2 * k]], 1);
        sl[2 * k + 1] = atomicAdd(&hcnt[bk[2 * k + 1]], 1);
    }
    __syncthreads();

    // exclusive scan over 1024 counts: 4-chunk local + Hillis-Steele over 256
    int c[4], loc[4];
    int s = 0;
#pragma unroll
    for (int q = 0; q < 4; ++q) {
        c[q] = hcnt[t * 4 + q];
        loc[q] = s;
        s += c[q];
    }
    ps[t] = s;
    __syncthreads();
    for (int off = 1; off < 256; off <<= 1) {
        int v = ps[t];
        int add = (t >= off) ? ps[t - off] : 0;
        __syncthreads();
        ps[t] = v + add;
        __syncthreads();
    }
    const int base = (t == 0) ? 0 : ps[t - 1];
    uint32* oc = ocnt + (size_t)blockIdx.x * NBUCK;
#pragma unroll
    for (int q = 0; q < 4; ++q) {
        int e0 = base + loc[q];
        lbase[t * 4 + q] = e0;
        oc[t * 4 + q] = (uint32)e0 | ((uint32)c[q] << 16);
    }
    __syncthreads();

#pragma unroll
    for (int k = 0; k < 8; ++k) st[lbase[bk[k]] + sl[k]] = pk[k];
    __syncthreads();
    uint32* gout = ebuf + (size_t)blockIdx.x * SPB;
#pragma unroll
    for (int k = 0; k < 8; ++k) gout[t + k * 256] = st[t + k * 256];
}

// ===== launch 2: parity-interleaved support (even) + degb (odd), 37 KB arena =====
__global__ __launch_bounds__(256) void mid_kernel(
    const uint32* __restrict__ ebuf, const uint32* __restrict__ ocnt,
    float* __restrict__ dis, int* __restrict__ degarr,
    ushort* __restrict__ dadj, const float* __restrict__ x,
    const float* __restrict__ gamma, const float* __restrict__ beta,
    const ushort* __restrict__ Wp, const float* __restrict__ base_b,
    ushort* __restrict__ S) {
    __shared__ __align__(16) ushort smem[16 * KPAD];        // 37,120 B
    const int t = threadIdx.x;
    const int lane = t & 63;
    const int w = t >> 6;

    if (blockIdx.x & 1) {
        // ---- degb: bucket of 16 nodes; bitmask 16*MROW*4 = 33,024 B ----
        uint32* mask = (uint32*)smem;
        const int bkt = blockIdx.x >> 1;
        for (int i = t; i < 16 * MROW; i += 256) mask[i] = 0;
        __syncthreads();

        for (int b = t; b < SBLK; b += 256) {
            uint32 oc = ocnt[(size_t)b * NBUCK + bkt];
            int off = (int)(oc & 0xFFFFu);
            int cn  = (int)(oc >> 16);
            const uint32* p = ebuf + (size_t)b * SPB + off;
            for (int s = 0; s < cn; ++s) {
                uint32 e = p[s];
                atomicOr(&mask[(e >> 14) * MROW + ((e & 16383) >> 5)],
                         1u << (e & 31));
            }
        }
        __syncthreads();

        // compaction: wave w -> nodes w*4 .. w*4+3; lane owns words lane+64j
        for (int n = w * 4; n < w * 4 + 4; ++n) {
            const uint32* row = &mask[n * MROW];
            uint32 wd[8];
            int c = 0;
#pragma unroll
            for (int j = 0; j < 8; ++j) {
                wd[j] = row[lane + 64 * j];
                c += __popc(wd[j]);
            }
            int inc = c;
#pragma unroll
            for (int o = 1; o < 64; o <<= 1) {
                int v = __shfl_up(inc, o);
                if (lane >= o) inc += v;
            }
            int total = __shfl(inc, 63);
            int pos = inc - c;
            const int node = bkt * 16 + n;
            if (lane == 0) {
                dis[node] = rsqrtf((float)total);
                degarr[node] = total > DCAP ? DCAP : total;
            }
            ushort* drow = dadj + (size_t)node * DCAP;
#pragma unroll
            for (int j = 0; j < 8; ++j) {
                uint32 bits = wd[j];
                int base = (lane + 64 * j) * 32;
                while (bits) {
                    int b = __ffs(bits) - 1;
                    bits &= bits - 1;
                    if (pos < DCAP) drow[pos] = (ushort)(base + b);
                    ++pos;
                }
            }
        }
        return;
    }

    // ---- support: 16 nodes/block, FastKAN basis + bf16 MFMA (unscaled S) ----
    ushort* Bs = smem;                                       // [16][KPAD]
    const int nodeBase = (blockIdx.x >> 1) * 16;

    const float g0 = gamma[lane], g1 = gamma[lane + 64];
    const float be0 = beta[lane], be1 = beta[lane + 64];

    for (int n = w * 4; n < w * 4 + 4; ++n) {
        const int row = nodeBase + n;
        float f0 = x[(size_t)row * 128 + lane];
        float f1 = x[(size_t)row * 128 + lane + 64];
        float s = f0 + f1;
#pragma unroll
        for (int o = 32; o; o >>= 1) s += __shfl_xor(s, o);
        float mu = s * 0.0078125f;
        float d0 = f0 - mu, d1 = f1 - mu;
        float v = d0 * d0 + d1 * d1;
#pragma unroll
        for (int o = 32; o; o >>= 1) v += __shfl_xor(v, o);
        float rstd = rsqrtf(v * 0.0078125f + 1e-5f);
        float h0 = d0 * rstd * g0 + be0;
        float h1 = d1 * rstd * g1 + be1;
        ushort pk0[8] __attribute__((aligned(16)));
        ushort pk1[8] __attribute__((aligned(16)));
#pragma unroll
        for (int g = 0; g < 8; ++g) {
            float gv = -2.0f + (float)g * (4.0f / 7.0f);
            float z0 = (h0 - gv) * 1.75f;
            float z1 = (h1 - gv) * 1.75f;
            pk0[g] = f2bf(__expf(-z0 * z0));
            pk1[g] = f2bf(__expf(-z1 * z1));
        }
        *reinterpret_cast<uint4*>(&Bs[n * KPAD + lane * 8]) =
            *reinterpret_cast<const uint4*>(pk0);
        *reinterpret_cast<uint4*>(&Bs[n * KPAD + (lane + 64) * 8]) =
            *reinterpret_cast<const uint4*>(pk1);
        Bs[n * KPAD + 1024 + lane]      = f2bf(f0 / (1.0f + __expf(-f0)));
        Bs[n * KPAD + 1024 + lane + 64] = f2bf(f1 / (1.0f + __expf(-f1)));
    }
    __syncthreads();

    const int ct0 = w * 2;
    f32x4 acc0 = {0.f, 0.f, 0.f, 0.f};
    f32x4 acc1 = {0.f, 0.f, 0.f, 0.f};
    const ushort* ArowBase = &Bs[(lane & 15) * KPAD + (lane >> 4) * 8];
    const bf16x8* Wv = (const bf16x8*)Wp;
#pragma unroll 4
    for (int kk = 0; kk < KSTEPS; ++kk) {
        bf16x8 a = *reinterpret_cast<const bf16x8*>(ArowBase + kk * 32);
        bf16x8 b0 = Wv[(size_t)(kk * 8 + ct0) * 64 + lane];
        bf16x8 b1 = Wv[(size_t)(kk * 8 + ct0 + 1) * 64 + lane];
        acc0 = __builtin_amdgcn_mfma_f32_16x16x32_bf16(a, b0, acc0, 0, 0, 0);
        acc1 = __builtin_amdgcn_mfma_f32_16x16x32_bf16(a, b1, acc1, 0, 0, 0);
    }

    const int col0 = ct0 * 16 + (lane & 15);
    const int rbase = (lane >> 4) * 4;
    const float bb0 = base_b[col0];
    const float bb1 = base_b[col0 + 16];
#pragma unroll
    for (int r = 0; r < 4; ++r) {
        const int row = nodeBase + rbase + r;
        S[(size_t)row * 128 + col0]      = f2bf(acc0[r] + bb0);
        S[(size_t)row * 128 + col0 + 16] = f2bf(acc1[r] + bb1);
    }
}

// ===== launch 3: aggregation, out[i] = dis_i * sum_j dis_j*S_j + bias =====
// 2 nodes per block; 128 threads per node
__global__ __launch_bounds__(256) void aggregate_kernel(
    const int* __restrict__ degarr, const ushort* __restrict__ dadj,
    const ushort* __restrict__ S, const float* __restrict__ dis,
    const float* __restrict__ bias, float* __restrict__ out) {
    __shared__ ushort lst[2][DCAP];
    __shared__ float part[2][2][128];
    const int t = threadIdx.x;
    const int g = t >> 7;
    const int tl = t & 127;
    const int i = blockIdx.x * 2 + g;

    const int total = degarr[i];
    const ushort* drow = dadj + (size_t)i * DCAP;
    if (tl < total) lst[g][tl] = drow[tl];
    if (tl + 128 < total) lst[g][tl + 128] = drow[tl + 128];
    __syncthreads();

    const int lane = t & 63;
    const int wv = (t >> 6) & 1;
    const uint32* S32 = (const uint32*)S;            // row stride 64 uints
    float a0 = 0.f, a1 = 0.f;
    int idx = wv;
    for (; idx + 6 < total; idx += 8) {
        int j0 = lst[g][idx], j1 = lst[g][idx + 2];
        int j2 = lst[g][idx + 4], j3 = lst[g][idx + 6];
        float d0 = dis[j0], d1 = dis[j1], d2 = dis[j2], d3 = dis[j3];
        uint32 u0 = S32[(size_t)j0 * 64 + lane];
        uint32 u1 = S32[(size_t)j1 * 64 + lane];
        uint32 u2 = S32[(size_t)j2 * 64 + lane];
        uint32 u3 = S32[(size_t)j3 * 64 + lane];
        a0 += (d0 * bflo(u0) + d1 * bflo(u1)) + (d2 * bflo(u2) + d3 * bflo(u3));
        a1 += (d0 * bfhi(u0) + d1 * bfhi(u1)) + (d2 * bfhi(u2) + d3 * bfhi(u3));
    }
    for (; idx < total; idx += 2) {
        int j = lst[g][idx];
        float d = dis[j];
        uint32 u = S32[(size_t)j * 64 + lane];
        a0 += d * bflo(u);
        a1 += d * bfhi(u);
    }
    part[g][wv][lane * 2]     = a0;
    part[g][wv][lane * 2 + 1] = a1;
    __syncthreads();

    float v = part[g][0][tl] + part[g][1][tl];
    out[(size_t)i * 128 + tl] = v * dis[i] + bias[tl];
}

extern "C" void kernel_launch(void* const* d_in, const int* in_sizes, int n_in,
                              void* d_out, int out_size, void* d_ws, size_t ws_size,
                              hipStream_t stream) {
    const float* x        = (const float*)d_in[0];
    const int*   ei       = (const int*)d_in[1];
    const float* ln_gamma = (const float*)d_in[2];
    const float* ln_beta  = (const float*)d_in[3];
    const float* spline_w = (const float*)d_in[4];
    const float* base_w   = (const float*)d_in[5];
    const float* base_b   = (const float*)d_in[6];
    const float* bias     = (const float*)d_in[7];
    float* out = (float*)d_out;

    char* ws = (char*)d_ws;
    const size_t WP_OFF   = 0;             //    294,912 B
    const size_t DIS_OFF  = 294912;        //     65,536 B
    const size_t DEG_OFF  = 360448;        //     65,536 B
    const size_t DADJ_OFF = 425984;        //  8,388,608 B
    const size_t OCNT_OFF = 8814592;       //  2,097,152 B (512 x 1024 u32)
    const size_t EBUF_OFF = 10911744;      //  4,194,304 B
    const size_t S_OFF    = 15106048;      //  4,194,304 B
    const size_t NEEDED   = 19300352;
    if (ws_size < NEEDED) return;

    ushort* Wp     = (ushort*)(ws + WP_OFF);
    float*  dis    = (float*)(ws + DIS_OFF);
    int*    degarr = (int*)(ws + DEG_OFF);
    ushort* dadj   = (ushort*)(ws + DADJ_OFF);
    uint32* ocnt   = (uint32*)(ws + OCNT_OFF);
    uint32* ebuf   = (uint32*)(ws + EBUF_OFF);
    ushort* S      = (ushort*)(ws + S_OFF);

    pre_kernel<<<SBLK + 576, 256, 0, stream>>>(ei, ebuf, ocnt,
                                               spline_w, base_w, Wp);
    mid_kernel<<<2048, 256, 0, stream>>>(ebuf, ocnt, dis, degarr, dadj,
                                         x, ln_gamma, ln_beta, Wp, base_b, S);
    aggregate_kernel<<<N_NODES / 2, 256, 0, stream>>>(degarr, dadj, S, dis,
                                                      bias, out);
}